// Round 6
// baseline (817.494 us; speedup 1.0000x reference)
//
#include <hip/hip_runtime.h>
#include <math.h>

#define SD_  (512*512)
#define BSD_ (16*512*512)

typedef unsigned short u16;
typedef short s16x8 __attribute__((ext_vector_type(8)));
typedef float f32x4 __attribute__((ext_vector_type(4)));

__device__ __forceinline__ float sigmoidf_(float x) { return 1.0f / (1.0f + __expf(-x)); }

__device__ __forceinline__ u16 f2bf(float f) {
    unsigned int u = __float_as_uint(f);
    u += 0x7fffu + ((u >> 16) & 1u);
    return (u16)(u >> 16);
}
__device__ __forceinline__ float bf2f(u16 h) { return __uint_as_float((unsigned)h << 16); }

__device__ __forceinline__ void glds16(const void* g, void* l) {
    __builtin_amdgcn_global_load_lds((const __attribute__((address_space(1))) unsigned int*)g,
                                     (__attribute__((address_space(3))) unsigned int*)l, 16, 0, 0);
}

// ---------------------------------------------------------------------------
// bf16 MFMA GEMM v3.1. Tile 128x64 (MxN), BK=32, 256 thr = 4 waves (wave 64x32,
// 4x2 mfma 16x16x32). A row-major [M][K], B ALWAYS N-major [N][K]; both staged
// via global_load_lds dwordx4 into fragment-major LDS (conflict-free).
// Double-buffered, 1 barrier/iter. 2-4 blocks/CU for barrier overlap.
// EPI: 0=store 1=+bias 3=+Cin 4=PReLU((acc+bS*bias+Cin)*invden) 6=sigm(+bias)
//      7=+bias+Cin 8=gate: sigm(acc+Cin)*sc[row]*Aeff(row,col)
// ASEL: A rows replaced by DG[seli[row]] where selm[row].
// TRW: transposed bf16 output. BATCH-AWARE: dst = CT + (row>>9)*sCT
//      + col*ldcT + (row&511)   (fixes R5's flat-M aliasing bug).
// ---------------------------------------------------------------------------
struct GP {
    const u16 *A1, *A2;  int lda1, lda2;  long sA;
    const u16 *B1, *B2;  int ldb1, ldb2;  long sB;
    void *C1, *C2;  int obf1, obf2, ldc1, ldc2;  long sC;
    u16 *CT1, *CT2;  int ldcT1, ldcT2;  long sCT;
    const void *Ci1, *Ci2;  int cbf1, cbf2, ldci1, ldci2;  long sCi1, sCi2;
    const float *bias;  float bS;
    const float *sc1, *sc2;
    const int *selm1, *seli1, *selm2, *seli2;
    const float *DG;
    const float *invden, *prelu;  int pidx;
    int M, K, zs, swzX, swzY;   // swzX/Y = log2(gridDim.x/y); swzX<0 = no swizzle
};

template<int EPI, int ASEL, int TRW>
__global__ __launch_bounds__(256, 4)
void gemm2(const GP p)
{
    __shared__ short LS[12288];   // 2 x (A 4096 + B 2048) shorts
    const int tid = threadIdx.x;
    int bx, by, bz;
    if (p.swzX >= 0) {
        const int bid = blockIdx.x + gridDim.x * (blockIdx.y + gridDim.y * blockIdx.z);
        const int ppx = (gridDim.y * gridDim.z) >> 3;
        const int xcd = bid & 7, idx = bid >> 3;
        const int pair = xcd * ppx + (idx >> p.swzX);
        bx = idx & ((1 << p.swzX) - 1);
        by = pair & ((1 << p.swzY) - 1);
        bz = pair >> p.swzY;
    } else { bx = blockIdx.x; by = blockIdx.y; bz = blockIdx.z; }

    const int seg = (bz >= p.zs) ? 1 : 0;
    const int z = seg ? bz - p.zs : bz;
    const u16* Ab = (seg ? p.A2 : p.A1) + z * p.sA;
    const int lda = seg ? p.lda2 : p.lda1;
    const u16* Bb = (seg ? p.B2 : p.B1) + z * p.sB;
    const int ldb = seg ? p.ldb2 : p.ldb1;

    const int m0 = by * 128, n0 = bx * 64;
    const int srow = ((tid >> 6) << 4) | (tid & 15);   // 0..63
    const int sk0 = ((tid >> 4) & 3) << 3;

    const u16* aRow0 = Ab + (long)(m0 + srow) * lda + sk0;
    const u16* aRow1 = aRow0 + (long)64 * lda;
    const u16* bRow  = Bb + (long)(n0 + srow) * ldb + sk0;

    int aselv0 = 0, aselv1 = 0; long dgo0 = 0, dgo1 = 0;
    if (ASEL) {
        const int* selm = seg ? p.selm2 : p.selm1;
        const int* seli = seg ? p.seli2 : p.seli1;
        const int r0 = m0 + srow, r1 = r0 + 64;
        aselv0 = selm[r0]; dgo0 = (long)(((r0 >> 9) << 3) + seli[r0]) * 512 + sk0;
        aselv1 = selm[r1]; dgo1 = (long)(((r1 >> 9) << 3) + seli[r1]) * 512 + sk0;
    }

    auto stage = [&](int kk, int buf) {
        short* base = &LS[buf * 6144];
        if (ASEL) {
            s16x8 v0, v1;
            if (aselv0) { const float* dg = p.DG + dgo0 + kk;
#pragma unroll
                for (int q = 0; q < 8; ++q) v0[q] = (short)f2bf(dg[q]); }
            else v0 = *(const s16x8*)(aRow0 + kk);
            if (aselv1) { const float* dg = p.DG + dgo1 + kk;
#pragma unroll
                for (int q = 0; q < 8; ++q) v1[q] = (short)f2bf(dg[q]); }
            else v1 = *(const s16x8*)(aRow1 + kk);
            *(s16x8*)&base[tid * 8] = v0;
            *(s16x8*)&base[2048 + tid * 8] = v1;
        } else {
            glds16(aRow0 + kk, &base[tid * 8]);
            glds16(aRow1 + kk, &base[2048 + tid * 8]);
        }
        glds16(bRow + kk, &base[4096 + tid * 8]);
    };

    const int wave = tid >> 6, lane = tid & 63;
    const int rowSelA = (wave >> 1) << 2;   // wm/16
    const int rowSelB = (wave & 1) << 1;    // wn/16

    f32x4 acc[4][2] = {};
    stage(0, 0);
    const int nkb = p.K >> 5;
    for (int kb = 0; kb < nkb; ++kb) {
        __syncthreads();
        if (kb + 1 < nkb) stage((kb + 1) << 5, (kb + 1) & 1);
        const short* ls = &LS[(kb & 1) * 6144];
        s16x8 aF[4], bF[2];
#pragma unroll
        for (int mt = 0; mt < 4; ++mt) aF[mt] = *(const s16x8*)&ls[((rowSelA + mt) * 64 + lane) * 8];
#pragma unroll
        for (int nt = 0; nt < 2; ++nt) bF[nt] = *(const s16x8*)&ls[4096 + ((rowSelB + nt) * 64 + lane) * 8];
#pragma unroll
        for (int mt = 0; mt < 4; ++mt)
#pragma unroll
            for (int nt = 0; nt < 2; ++nt)
                acc[mt][nt] = __builtin_amdgcn_mfma_f32_16x16x32_bf16(aF[mt], bF[nt], acc[mt][nt], 0, 0, 0);
    }

    // ---- epilogue ----
    const int ml = lane & 15, quad = lane >> 4;
    const int wm = (wave >> 1) * 64, wn = (wave & 1) * 32;
    u16* Cb16 = (u16*)(seg ? p.C2 : p.C1);
    float* Cb32 = (float*)(seg ? p.C2 : p.C1);
    const int haveC = (seg ? p.C2 : p.C1) != nullptr;
    const int obf = seg ? p.obf2 : p.obf1;
    const int ldc = seg ? p.ldc2 : p.ldc1;
    if (haveC) { if (obf) Cb16 += z * p.sC; else Cb32 += z * p.sC; }
    u16* CTb = (TRW ? (seg ? p.CT2 : p.CT1) : nullptr);
    const int ldcT = seg ? p.ldcT2 : p.ldcT1;
    if (TRW && CTb) CTb += z * p.sCT;
    const u16* Ci16 = (const u16*)(seg ? p.Ci2 : p.Ci1);
    const float* Ci32 = (const float*)(seg ? p.Ci2 : p.Ci1);
    const int cbf = seg ? p.cbf2 : p.cbf1;
    const int ldci = seg ? p.ldci2 : p.ldci1;
    {
        const long sCi = seg ? p.sCi2 : p.sCi1;
        if (cbf) Ci16 += z * sCi; else Ci32 += z * sCi;
    }
    const float pal = (EPI == 4) ? p.prelu[p.pidx] : 0.0f;
    const float* scp = (EPI == 8) ? (seg ? p.sc2 : p.sc1) : nullptr;
    const int* eselm = (EPI == 8) ? (seg ? p.selm2 : p.selm1) : nullptr;
    const int* eseli = (EPI == 8) ? (seg ? p.seli2 : p.seli1) : nullptr;

#pragma unroll
    for (int mt = 0; mt < 4; ++mt) {
#pragma unroll
        for (int nt = 0; nt < 2; ++nt) {
            const int col = n0 + wn + nt * 16 + ml;
            u16 pk[4];
#pragma unroll
            for (int r = 0; r < 4; ++r) {
                const int row = m0 + wm + mt * 16 + quad * 4 + r;
                float x = acc[mt][nt][r];
                float cin = 0.0f;
                if (EPI == 3 || EPI == 4 || EPI == 7 || EPI == 8)
                    cin = cbf ? bf2f(Ci16[(long)row * ldci + col]) : Ci32[(long)row * ldci + col];
                if (EPI == 1) x += p.bias[col];
                else if (EPI == 3) x += cin;
                else if (EPI == 4) {
                    x = (x + p.bS * p.bias[col] + cin) * p.invden[z * p.M + row];
                    x = (x >= 0.0f) ? x : pal * x;
                }
                else if (EPI == 6) x = sigmoidf_(x + p.bias[col]);
                else if (EPI == 7) x += p.bias[col] + cin;
                else if (EPI == 8) {
                    float av;
                    if (eselm[row]) av = p.DG[(long)(((row >> 9) << 3) + eseli[row]) * 512 + col];
                    else av = bf2f(Ab[(long)row * lda + col]);
                    x = sigmoidf_(x + cin) * scp[row] * av;
                }
                if (haveC) { if (obf) Cb16[(long)row * ldc + col] = f2bf(x); else Cb32[(long)row * ldc + col] = x; }
                pk[r] = f2bf(x);
            }
            if (TRW && CTb) {
                const int mrow = m0 + wm + mt * 16 + quad * 4;
                // batch-aware transposed address (mrow..mrow+3 are within one batch)
                u16* ct = CTb + ((long)(mrow >> 9)) * p.sCT + (long)col * ldcT + (mrow & 511);
                *(ushort4*)ct = *(ushort4*)pk;
            }
        }
    }
}

// --------------------------- pre-pass conversions ---------------------------
__global__ __launch_bounds__(256)
void cvt_k(const float* __restrict__ s, u16* __restrict__ d)
{
    const long i = ((long)blockIdx.x * 256 + threadIdx.x) * 4;
    const float4 v = *(const float4*)&s[i];
    ushort4 h = { f2bf(v.x), f2bf(v.y), f2bf(v.z), f2bf(v.w) };
    *(ushort4*)&d[i] = h;
}

// batched transpose+cvt: src[z] RxC fp32 -> dstT[z] CxR bf16 (+ optional normal copy)
__global__ __launch_bounds__(256)
void trcvt_k(const float* __restrict__ src, u16* __restrict__ dstT, u16* __restrict__ dstN,
             const int R, const int C, const long sS, const long sDT, const long sDN)
{
    __shared__ u16 t[64][72];
    const float* s = src + blockIdx.z * sS;
    const int r0 = blockIdx.y * 64, c0 = blockIdx.x * 64;
    const int tid = threadIdx.x;
    const int lr = tid >> 2, lc4 = (tid & 3) * 16;
#pragma unroll
    for (int j = 0; j < 4; ++j) {
        const float4 v = *(const float4*)&s[(long)(r0 + lr) * C + c0 + lc4 + j * 4];
        ushort4 h = { f2bf(v.x), f2bf(v.y), f2bf(v.z), f2bf(v.w) };
        *(ushort4*)&t[lr][lc4 + j * 4] = h;
        if (dstN) *(ushort4*)&dstN[blockIdx.z * sDN + (long)(r0 + lr) * C + c0 + lc4 + j * 4] = h;
    }
    __syncthreads();
    const int lcol = tid >> 2, rc = (tid & 3) * 16;
#pragma unroll
    for (int j = 0; j < 2; ++j) {
        s16x8 v;
#pragma unroll
        for (int q = 0; q < 8; ++q) v[q] = (short)t[rc + j * 8 + q][lcol];
        *(s16x8*)&dstT[blockIdx.z * sDT + (long)(c0 + lcol) * R + r0 + rc + j * 8] = v;
    }
}

// ---------------------------------------------------------------------------
__global__ __launch_bounds__(256)
void e0_k(const float* __restrict__ adj, const float* __restrict__ depmap,
          const float* __restrict__ domain_id, const float* __restrict__ redomain_id,
          float* __restrict__ invden, float* __restrict__ fa, int* __restrict__ dcol,
          int* __restrict__ dm, int* __restrict__ dsel, int* __restrict__ rm, int* __restrict__ rsel)
{
    const int bs = blockIdx.x;
    const int t = threadIdx.x;
    const float* arow = adj + (long)bs * 512;
    const float* drow = depmap + (long)bs * 512;
    __shared__ float red[256];
    __shared__ int scol;
    if (t == 0) scol = 0;
    const float a0 = arow[t], a1 = arow[t + 256];
    const float p0 = drow[t], p1 = drow[t + 256];
    if (p0 > 0.5f) scol = t;
    if (p1 > 0.5f) scol = t + 256;
    red[t] = a0 + a1;
    __syncthreads();
    for (int off = 128; off > 0; off >>= 1) { if (t < off) red[t] += red[t + off]; __syncthreads(); }
    if (t == 0) invden[bs] = 1.0f / (red[0] + 1.0f);
    __syncthreads();
    red[t] = a0 * p0 + a1 * p1;
    __syncthreads();
    for (int off = 128; off > 0; off >>= 1) { if (t < off) red[t] += red[t + off]; __syncthreads(); }
    if (t == 0) {
        fa[bs] = red[0];
        dcol[bs] = scol;
        const float* q = domain_id + (long)bs * 8;
        float s = 0.f; int sel = 0;
        for (int k = 0; k < 8; ++k) { float v = q[k]; s += v; if (v > 0.5f) sel = k; }
        dm[bs] = (s > 0.5f) ? 1 : 0; dsel[bs] = sel;
        const float* r = redomain_id + (long)bs * 8;
        s = 0.f; sel = 0;
        for (int k = 0; k < 8; ++k) { float v = r[k]; s += v; if (v > 0.5f) sel = k; }
        rm[bs] = (s > 0.5f) ? 1 : 0; rsel[bs] = sel;
    }
}

__global__ void e0b_k(const float* __restrict__ adj, const int* __restrict__ dcol, float* __restrict__ ba)
{
    const int bs = blockIdx.x * 256 + threadIdx.x;
    const int b = bs >> 9, s = bs & 511;
    ba[bs] = adj[((long)b * 512 + dcol[bs]) * 512 + s];
}

// pool pass1 (chunked masked max) + OxR^T = (OUT .* rel)^T, all bf16
__global__ __launch_bounds__(256)
void pool1_k(const u16* __restrict__ OUT, const int ldO, const int* __restrict__ domain,
             const u16* __restrict__ relb, u16* __restrict__ cm, u16* __restrict__ OxRT)
{
    const int b = blockIdx.x >> 4, c = blockIdx.x & 15;
    const int s0 = c * 32, tid = threadIdx.x;
    __shared__ int dom[256];
    dom[tid] = domain[((long)(b * 512 + s0 + (tid >> 3))) * 8 + (tid & 7)];
    __syncthreads();
    const int d0 = tid * 2;
    float mxa[8], mxb[8];
#pragma unroll
    for (int k = 0; k < 8; ++k) { mxa[k] = -10000.0f; mxb[k] = -10000.0f; }
    s16x8 pA[4], pB[4];
#pragma unroll
    for (int s = 0; s < 32; ++s) {
        const int row = b * 512 + s0 + s;
        const unsigned uv = *(const unsigned*)&OUT[(long)row * ldO + d0];
        const unsigned rv = *(const unsigned*)&relb[(long)row * 512 + d0];
        const float vx = bf2f((u16)(uv & 0xffff)), vy = bf2f((u16)(uv >> 16));
        const float rx = bf2f((u16)(rv & 0xffff)), ry = bf2f((u16)(rv >> 16));
        pA[s >> 3][s & 7] = (short)f2bf(vx * rx);
        pB[s >> 3][s & 7] = (short)f2bf(vy * ry);
        const int* ds = &dom[s * 8];
#pragma unroll
        for (int k = 0; k < 8; ++k) {
            mxa[k] = fmaxf(mxa[k], ds[k] ? -10000.0f : vx);
            mxb[k] = fmaxf(mxb[k], ds[k] ? -10000.0f : vy);
        }
    }
#pragma unroll
    for (int j = 0; j < 4; ++j) *(s16x8*)&OxRT[((long)b * 512 + d0) * 512 + s0 + j * 8] = pA[j];
#pragma unroll
    for (int j = 0; j < 4; ++j) *(s16x8*)&OxRT[((long)b * 512 + d0 + 1) * 512 + s0 + j * 8] = pB[j];
#pragma unroll
    for (int k = 0; k < 8; ++k) {
        ushort2 h = { f2bf(mxa[k]), f2bf(mxb[k]) };
        *(ushort2*)&cm[((long)((b * 16 + c) * 8 + k)) * 512 + d0] = h;
    }
}

__global__ void pool2_k(const u16* __restrict__ cm, u16* __restrict__ pooled)
{
    const int q = blockIdx.x * 256 + threadIdx.x;      // 65536
    const int b = q >> 12, k = (q >> 9) & 7, d = q & 511;
    float m = -1e30f;
    for (int c = 0; c < 16; ++c)
        m = fmaxf(m, bf2f(cm[((long)((b * 16 + c) * 8 + k)) * 512 + d]));
    pooled[((long)(b * 8 + k)) * 512 + d] = f2bf(m);
}

extern "C" void kernel_launch(void* const* d_in, const int* in_sizes, int n_in,
                              void* d_out, int out_size, void* d_ws, size_t ws_size,
                              hipStream_t stream)
{
    const float* adj         = (const float*)d_in[0];
    const int*   domain      = (const int*)d_in[1];
    const float* domain_id   = (const float*)d_in[2];
    const float* redomain_id = (const float*)d_in[3];
    const float* frontrel    = (const float*)d_in[4];
    const float* backrel     = (const float*)d_in[5];
    const float* depmap      = (const float*)d_in[6];
    const float* rel         = (const float*)d_in[7];
    const float* gcn         = (const float*)d_in[8];
    const float* W_layers    = (const float*)d_in[10];
    const float* b_layers    = (const float*)d_in[11];
    const float* prelu_a     = (const float*)d_in[12];
    const float* W_dg        = (const float*)d_in[13];
    const float* b_dg        = (const float*)d_in[14];
    const float* W_mg        = (const float*)d_in[15];
    const float* b_mg        = (const float*)d_in[16];
    const float* W_out       = (const float*)d_in[17];
    const float* b_out       = (const float*)d_in[18];
    float* out = (float*)d_out;

    char* w = (char*)d_ws;
    auto alloc = [&](size_t bytes) { void* p = (void*)w; w += (bytes + 255) & ~(size_t)255; return p; };
    const size_t Bb = (size_t)BSD_ * 2;
    u16* OUTS_bf = (u16*)alloc((size_t)8192 * 1536 * 2);
    u16* OUTT    = (u16*)alloc(Bb);   // current layer output, transposed per batch [b][d][s]
    u16* gcnT    = (u16*)alloc(Bb);
    u16* RB_bf   = (u16*)alloc(Bb);
    u16* XB_bf   = (u16*)alloc(Bb);
    u16* XFT_bf  = (u16*)alloc(Bb);   // XF transposed per batch [b][d][s]
    u16* OxRT_bf = (u16*)alloc(Bb);
    u16* DL_bf   = (u16*)alloc(Bb);
    u16* AXO_bf  = (u16*)alloc(Bb);
    u16* BB_bf   = (u16*)alloc(Bb);
    u16* FB_bf   = (u16*)alloc(Bb);
    u16* rel_bf  = (u16*)alloc(Bb);
    u16* relT_bf = (u16*)alloc(Bb);
    u16* adj_bf  = (u16*)alloc(Bb);
    u16* gcn_bf  = (u16*)alloc(Bb);
    u16* frel_bf = (u16*)alloc(Bb);
    u16* brel_bf = (u16*)alloc(Bb);
    u16* WmgT1 = (u16*)alloc((size_t)SD_ * 2);
    u16* WmgT2 = (u16*)alloc((size_t)SD_ * 2);
    u16* WdgT  = (u16*)alloc((size_t)SD_ * 2);
    u16* WlT   = (u16*)alloc((size_t)3 * SD_ * 2);
    u16* WoutT = (u16*)alloc((size_t)512 * 1536 * 2);
    u16* cm     = (u16*)alloc((size_t)16 * 16 * 8 * 512 * 2);
    u16* pooled = (u16*)alloc((size_t)16 * 8 * 512 * 2);
    float* DG     = (float*)alloc((size_t)16 * 8 * 512 * 4);
    float* invden = (float*)alloc(8192 * 4);
    float* fa     = (float*)alloc(8192 * 4);
    float* ba     = (float*)alloc(8192 * 4);
    int* dcol = (int*)alloc(8192 * 4);
    int* dm   = (int*)alloc(8192 * 4);
    int* dsel = (int*)alloc(8192 * 4);
    int* rm   = (int*)alloc(8192 * 4);
    int* rsel = (int*)alloc(8192 * 4);

    // ---- pre-pass ----
    cvt_k<<<4096, 256, 0, stream>>>(adj, adj_bf);
    cvt_k<<<4096, 256, 0, stream>>>(frontrel, frel_bf);
    cvt_k<<<4096, 256, 0, stream>>>(backrel, brel_bf);
    trcvt_k<<<dim3(8, 8, 16), 256, 0, stream>>>(gcn, gcnT, gcn_bf, 512, 512, SD_, SD_, SD_);
    trcvt_k<<<dim3(8, 8, 16), 256, 0, stream>>>(rel, relT_bf, rel_bf, 512, 512, SD_, SD_, SD_);
    trcvt_k<<<dim3(8, 8, 1), 256, 0, stream>>>(W_mg, WmgT1, nullptr, 512, 512, 0, 0, 0);
    trcvt_k<<<dim3(8, 8, 1), 256, 0, stream>>>(W_mg + SD_, WmgT2, nullptr, 512, 512, 0, 0, 0);
    trcvt_k<<<dim3(8, 8, 1), 256, 0, stream>>>(W_dg, WdgT, nullptr, 512, 512, 0, 0, 0);
    trcvt_k<<<dim3(8, 8, 3), 256, 0, stream>>>(W_layers, WlT, nullptr, 512, 512, SD_, SD_, 0);
    trcvt_k<<<dim3(8, 24, 1), 256, 0, stream>>>(W_out, WoutT, nullptr, 1536, 512, 0, 0, 0);
    e0_k<<<8192, 256, 0, stream>>>(adj, depmap, domain_id, redomain_id, invden, fa, dcol, dm, dsel, rm, rsel);
    e0b_k<<<32, 256, 0, stream>>>(adj, dcol, ba);

    const dim3 blk(256);

    // BB/FB = {back,front}rel @ W_mg[512:1024] + b_mg   (z=2 merged, 1024 blocks)
    {
        GP p{};
        p.A1 = brel_bf; p.A2 = frel_bf; p.lda1 = p.lda2 = 512; p.sA = 0;
        p.B1 = p.B2 = WmgT2; p.ldb1 = p.ldb2 = 512; p.sB = 0;
        p.C1 = BB_bf; p.C2 = FB_bf; p.obf1 = p.obf2 = 1; p.ldc1 = p.ldc2 = 512; p.sC = 0;
        p.bias = b_mg; p.M = 8192; p.K = 512; p.zs = 1; p.swzX = 3; p.swzY = 6;
        gemm2<1, 0, 0><<<dim3(8, 64, 2), blk, 0, stream>>>(p);
    }

    for (int l = 0; l < 3; ++l) {
        const u16* OUTp  = (l == 0) ? gcn_bf : (OUTS_bf + (l - 1) * 512);
        const u16* OUTTp = (l == 0) ? gcnT : OUTT;
        const int ldO = (l == 0) ? 512 : 1536;
        const long sO = (long)512 * ldO;

        // RB = rel @ outputs   (B = OUT^T, N-major)
        {
            GP p{};
            p.A1 = rel_bf; p.lda1 = 512; p.sA = SD_;
            p.B1 = OUTTp; p.ldb1 = 512; p.sB = SD_;
            p.C1 = RB_bf; p.obf1 = 1; p.ldc1 = 512; p.sC = SD_;
            p.M = 512; p.K = 512; p.zs = 16; p.swzX = 3; p.swzY = 2;
            gemm2<0, 0, 0><<<dim3(8, 4, 16), blk, 0, stream>>>(p);
        }
        pool1_k<<<256, 256, 0, stream>>>(OUTp, ldO, domain, rel_bf, cm, OxRT_bf);
        pool2_k<<<256, 256, 0, stream>>>(cm, pooled);
        {
            GP p{};
            p.A1 = pooled; p.lda1 = 512; p.B1 = WdgT; p.ldb1 = 512;
            p.C1 = DG; p.obf1 = 0; p.ldc1 = 512;
            p.bias = b_dg; p.M = 128; p.K = 512; p.zs = 1; p.swzX = -1;
            gemm2<6, 0, 0><<<dim3(8, 1, 1), blk, 0, stream>>>(p);
        }
        // merged gates: z0: XB = ba*sigm(RBeff@W1+BB)*RBeff (normal)
        //               z1: XF = fa*sigm(FOeff@W1+FB)*FOeff -> XF^T (batch-aware TRW)
        {
            GP p{};
            p.A1 = RB_bf; p.lda1 = 512; p.A2 = OUTp; p.lda2 = ldO; p.sA = 0;
            p.selm1 = rm; p.seli1 = rsel; p.selm2 = dm; p.seli2 = dsel; p.DG = DG;
            p.B1 = p.B2 = WmgT1; p.ldb1 = p.ldb2 = 512; p.sB = 0;
            p.Ci1 = BB_bf; p.Ci2 = FB_bf; p.cbf1 = p.cbf2 = 1; p.ldci1 = p.ldci2 = 512; p.sCi1 = p.sCi2 = 0;
            p.C1 = XB_bf; p.C2 = nullptr; p.obf1 = 1; p.ldc1 = 512; p.sC = 0;
            p.CT1 = nullptr; p.CT2 = XFT_bf; p.ldcT2 = 512; p.sCT = SD_;   // per-batch [b][d][s]
            p.sc1 = ba; p.sc2 = fa; p.M = 8192; p.K = 512; p.zs = 1; p.swzX = 3; p.swzY = 6;
            gemm2<8, 1, 1><<<dim3(8, 64, 2), blk, 0, stream>>>(p);
        }
        // merged: z<16: DL = rel^T @ XF + XB ; z>=16: AXO = adj @ OxR + outputs
        {
            GP p{};
            p.A1 = relT_bf; p.lda1 = 512; p.A2 = adj_bf; p.lda2 = 512; p.sA = SD_;
            p.B1 = XFT_bf; p.ldb1 = 512;
            p.B2 = OxRT_bf; p.ldb2 = 512; p.sB = SD_;
            p.Ci1 = XB_bf; p.cbf1 = 1; p.ldci1 = 512; p.sCi1 = SD_;
            p.Ci2 = OUTp; p.cbf2 = 1; p.ldci2 = ldO; p.sCi2 = sO;
            p.C1 = DL_bf; p.C2 = AXO_bf; p.obf1 = p.obf2 = 1; p.ldc1 = p.ldc2 = 512; p.sC = SD_;
            p.M = 512; p.K = 512; p.zs = 16; p.swzX = 3; p.swzY = 2;
            gemm2<3, 0, 0><<<dim3(8, 4, 32), blk, 0, stream>>>(p);
        }
        // outs[l] = PReLU((AXO@W + 2b + DL)*invden) -> OUTS stripe l (normal) + OUTT (transposed)
        {
            GP p{};
            p.A1 = AXO_bf; p.lda1 = 512; p.sA = SD_;
            p.B1 = WlT + (long)l * SD_; p.ldb1 = 512; p.sB = 0;
            p.Ci1 = DL_bf; p.cbf1 = 1; p.ldci1 = 512; p.sCi1 = SD_;
            p.C1 = OUTS_bf + l * 512; p.obf1 = 1; p.ldc1 = 1536; p.sC = (long)512 * 1536;
            p.CT1 = OUTT; p.ldcT1 = 512; p.sCT = SD_;
            p.bias = b_layers + l * 512; p.bS = 2.0f;
            p.invden = invden; p.prelu = prelu_a; p.pidx = l;
            p.M = 512; p.K = 512; p.zs = 16; p.swzX = 3; p.swzY = 2;
            gemm2<4, 0, 1><<<dim3(8, 4, 16), blk, 0, stream>>>(p);
        }
    }

    // out = OUTS @ W_out + b_out + gcn   (K=1536, fp32 out)
    {
        GP p{};
        p.A1 = OUTS_bf; p.lda1 = 1536; p.sA = 0;
        p.B1 = WoutT; p.ldb1 = 1536; p.sB = 0;
        p.Ci1 = gcn; p.cbf1 = 0; p.ldci1 = 512; p.sCi1 = 0;
        p.C1 = out; p.obf1 = 0; p.ldc1 = 512; p.sC = 0;
        p.bias = b_out; p.M = 8192; p.K = 1536; p.zs = 1; p.swzX = 3; p.swzY = 6;
        gemm2<7, 0, 0><<<dim3(8, 64, 1), blk, 0, stream>>>(p);
    }
}

// Round 7
// 711.737 us; speedup vs baseline: 1.1486x; 1.1486x over previous
//
#include <hip/hip_runtime.h>
#include <math.h>

#define SD_  (512*512)
#define BSD_ (16*512*512)

typedef unsigned short u16;
typedef short s16x8 __attribute__((ext_vector_type(8)));
typedef float f32x4 __attribute__((ext_vector_type(4)));

__device__ __forceinline__ float sigmoidf_(float x) { return 1.0f / (1.0f + __expf(-x)); }

__device__ __forceinline__ u16 f2bf(float f) {
    unsigned int u = __float_as_uint(f);
    u += 0x7fffu + ((u >> 16) & 1u);
    return (u16)(u >> 16);
}
__device__ __forceinline__ float bf2f(u16 h) { return __uint_as_float((unsigned)h << 16); }

__device__ __forceinline__ void glds16(const void* g, void* l) {
    __builtin_amdgcn_global_load_lds((const __attribute__((address_space(1))) unsigned int*)g,
                                     (__attribute__((address_space(3))) unsigned int*)l, 16, 0, 0);
}

// ---------------------------------------------------------------------------
// bf16 MFMA GEMM v4. Tile 128x128, BK=32, 512 thr = 8 waves (wave 64x32, 4x2
// mfma 16x16x32). A row-major [M][K], B N-major [N][K]; staged via
// global_load_lds dwordx4 into fragment-major LDS. 2-DEEP pipeline: 4 LDS
// buffers, stage k+2 issued at iter k, raw s_barrier + asm vmcnt(N) (no
// vmcnt(0) drain). Stores: fp32 direct / bf16 transposed 8B direct /
// bf16 normal via padded-LDS coalesce (16B). Cin: fp32 normal scalar or
// bf16 transposed ushort4.
// EPI: 0=store 1=+bias 3=+Cin 4=PReLU((acc+bS*bias+Cin)*invden) 6=sigm(+bias)
//      7=+bias+Cin 8=gate: sigm(acc+Cin)*sc[row]*Aeff(row,col)
// ASEL: A rows replaced by DG[seli[row]] where selm[row] (compiler-managed
// loads + ds_write + lgkmcnt(0) before barrier; B still glds-pipelined).
// ---------------------------------------------------------------------------
struct GP {
    const u16 *A1, *A2;  int lda1, lda2;  long sA;
    const u16 *B1, *B2;  int ldb1, ldb2;  long sB;
    void *C1, *C2;  int obf1, obf2, ldc1, ldc2;  long sC;   // obf: 0=fp32 direct, 1=bf16 LDS-coalesced
    u16 *CT1, *CT2;  long sCT;                              // transposed [b][d][s] (ld=512, batch SD_)
    const void *Ci1, *Ci2;  int cm1, cm2, ldci1, ldci2;  long sCi1, sCi2;  // cm: 0=fp32 normal, 1=bf16 transposed
    const float *bias;  float bS;
    const float *sc1, *sc2;
    const int *selm1, *seli1, *selm2, *seli2;
    const float *DG;
    const float *invden, *prelu;  int pidx;
    int M, K, zs, swzX, swzY;
};

template<int EPI, int ASEL>
__global__ __launch_bounds__(512, 4)
void gemm3(const GP p)
{
    __shared__ short LS[32768];   // 64 KB: 4 bufs x (A 4096 + B 4096 shorts)
    const int tid = threadIdx.x;
    int bx, by, bz;
    if (p.swzX >= 0) {
        const int bid = blockIdx.x + gridDim.x * (blockIdx.y + gridDim.y * blockIdx.z);
        const int ppx = (gridDim.y * gridDim.z) >> 3;
        const int xcd = bid & 7, idx = bid >> 3;
        const int pair = xcd * ppx + (idx >> p.swzX);
        bx = idx & ((1 << p.swzX) - 1);
        by = pair & ((1 << p.swzY) - 1);
        bz = pair >> p.swzY;
    } else { bx = blockIdx.x; by = blockIdx.y; bz = blockIdx.z; }

    const int seg = (bz >= p.zs) ? 1 : 0;
    const int z = seg ? bz - p.zs : bz;
    const u16* Ab = (seg ? p.A2 : p.A1) + z * p.sA;
    const int lda = seg ? p.lda2 : p.lda1;
    const u16* Bb = (seg ? p.B2 : p.B1) + z * p.sB;
    const int ldb = seg ? p.ldb2 : p.ldb1;

    const int m0 = by * 128, n0 = bx * 128;
    const int srow = ((tid >> 6) << 4) | (tid & 15);   // 0..127
    const int sk0 = ((tid >> 4) & 3) << 3;

    const u16* aRow = Ab + (long)(m0 + srow) * lda + sk0;
    const u16* bRow = Bb + (long)(n0 + srow) * ldb + sk0;

    int aselv = 0; long dgo = 0;
    if (ASEL) {
        const int* selm = seg ? p.selm2 : p.selm1;
        const int* seli = seg ? p.seli2 : p.seli1;
        const int r0 = m0 + srow;
        aselv = selm[r0];
        dgo = (long)(((r0 >> 9) << 3) + seli[r0]) * 512 + sk0;
    }

    auto stage = [&](int kk, int buf) {
        short* base = &LS[buf * 8192];
        if (ASEL) {
            s16x8 v;
            if (aselv) {
                const float* dg = p.DG + dgo + kk;
#pragma unroll
                for (int q = 0; q < 8; ++q) v[q] = (short)f2bf(dg[q]);
            } else v = *(const s16x8*)(aRow + kk);
            *(s16x8*)&base[tid * 8] = v;
        } else {
            glds16(aRow + kk, &base[tid * 8]);
        }
        glds16(bRow + kk, &base[4096 + tid * 8]);
    };

    const int wave = tid >> 6, lane = tid & 63;
    const int gA = (wave >> 2) << 2;   // A group base (wm/16)
    const int gB = (wave & 3) << 1;    // B group base (wn/16)

    f32x4 acc[4][2] = {};
    const int nkb = p.K >> 5;
    stage(0, 0);
    stage(32, 1);
    for (int kb = 0; kb < nkb; ++kb) {
        if (kb + 2 < nkb) stage((kb + 2) << 5, (kb + 2) & 3);
        const int ahead = (nkb - 1 - kb) < 2 ? (nkb - 1 - kb) : 2;
        if (ASEL) {
            if (ahead == 2)      asm volatile("s_waitcnt vmcnt(2)" ::: "memory");
            else if (ahead == 1) asm volatile("s_waitcnt vmcnt(1)" ::: "memory");
            else                 asm volatile("s_waitcnt vmcnt(0)" ::: "memory");
            asm volatile("s_waitcnt lgkmcnt(0)" ::: "memory");
        } else {
            if (ahead == 2)      asm volatile("s_waitcnt vmcnt(4)" ::: "memory");
            else if (ahead == 1) asm volatile("s_waitcnt vmcnt(2)" ::: "memory");
            else                 asm volatile("s_waitcnt vmcnt(0)" ::: "memory");
        }
        __builtin_amdgcn_s_barrier();
        const short* ls = &LS[(kb & 3) * 8192];
        s16x8 aF[4], bF[2];
#pragma unroll
        for (int mt = 0; mt < 4; ++mt) aF[mt] = *(const s16x8*)&ls[((gA + mt) * 64 + lane) * 8];
#pragma unroll
        for (int nt = 0; nt < 2; ++nt) bF[nt] = *(const s16x8*)&ls[4096 + ((gB + nt) * 64 + lane) * 8];
#pragma unroll
        for (int mt = 0; mt < 4; ++mt)
#pragma unroll
            for (int nt = 0; nt < 2; ++nt)
                acc[mt][nt] = __builtin_amdgcn_mfma_f32_16x16x32_bf16(aF[mt], bF[nt], acc[mt][nt], 0, 0, 0);
    }

    // ---- epilogue ----
    const int ml = lane & 15, quad = lane >> 4;
    const int wm = (wave >> 2) * 64, wn = (wave & 3) * 32;
    u16* Cb16 = (u16*)(seg ? p.C2 : p.C1);
    float* Cb32 = (float*)(seg ? p.C2 : p.C1);
    const int haveC = (seg ? p.C2 : p.C1) != nullptr;
    const int obf = seg ? p.obf2 : p.obf1;
    const int ldc = seg ? p.ldc2 : p.ldc1;
    if (haveC) { if (obf) Cb16 += z * p.sC; else Cb32 += z * p.sC; }
    u16* CTb = seg ? p.CT2 : p.CT1;
    if (CTb) CTb += z * p.sCT;
    const u16* CiT = (const u16*)(seg ? p.Ci2 : p.Ci1);
    const float* Ci32 = (const float*)(seg ? p.Ci2 : p.Ci1);
    const int cm = seg ? p.cm2 : p.cm1;
    const int ldci = seg ? p.ldci2 : p.ldci1;
    {
        const long sCi = seg ? p.sCi2 : p.sCi1;
        if (cm) CiT += z * sCi; else Ci32 += z * sCi;
    }
    const float pal = (EPI == 4) ? p.prelu[p.pidx] : 0.0f;
    const float* scp = (EPI == 8) ? (seg ? p.sc2 : p.sc1) : nullptr;
    const int* eselm = (EPI == 8) ? (seg ? p.selm2 : p.selm1) : nullptr;
    const int* eseli = (EPI == 8) ? (seg ? p.selm2 ? (seg ? p.seli2 : p.seli1) : p.seli1 : p.seli1) : nullptr;
    const int* eseli2 = (EPI == 8) ? (seg ? p.seli2 : p.seli1) : nullptr;

    const bool useEp = haveC && (obf == 1);
    u16* epbuf = (u16*)LS;
    if (useEp) __syncthreads();   // all waves done with K-loop LDS

#pragma unroll
    for (int mt = 0; mt < 4; ++mt) {
#pragma unroll
        for (int nt = 0; nt < 2; ++nt) {
            const int col = n0 + wn + nt * 16 + ml;
            const int rowb = m0 + wm + mt * 16 + quad * 4;
            float cin4[4];
            if (EPI == 3 || EPI == 4 || EPI == 7 || EPI == 8) {
                if (cm) {
                    const ushort4 c4 = *(const ushort4*)&CiT[(long)(rowb >> 9) * SD_ + (long)col * 512 + (rowb & 511)];
                    cin4[0] = bf2f(c4.x); cin4[1] = bf2f(c4.y); cin4[2] = bf2f(c4.z); cin4[3] = bf2f(c4.w);
                } else {
#pragma unroll
                    for (int r = 0; r < 4; ++r) cin4[r] = Ci32[(long)(rowb + r) * ldci + col];
                }
            }
            u16 pk[4];
#pragma unroll
            for (int r = 0; r < 4; ++r) {
                const int row = rowb + r;
                float x = acc[mt][nt][r];
                if (EPI == 1) x += p.bias[col];
                else if (EPI == 3) x += cin4[r];
                else if (EPI == 4) {
                    x = (x + p.bS * p.bias[col] + cin4[r]) * p.invden[z * p.M + row];
                    x = (x >= 0.0f) ? x : pal * x;
                }
                else if (EPI == 6) x = sigmoidf_(x + p.bias[col]);
                else if (EPI == 7) x += p.bias[col] + cin4[r];
                else if (EPI == 8) {
                    float av;
                    if (eselm[row]) av = p.DG[(long)(((row >> 9) << 3) + eseli2[row]) * 512 + col];
                    else av = bf2f(Ab[(long)row * lda + col]);
                    x = sigmoidf_(x + cin4[r]) * scp[row] * av;
                }
                if (haveC && obf == 0) Cb32[(long)row * ldc + col] = x;
                pk[r] = f2bf(x);
                if (useEp) epbuf[(wm + mt * 16 + quad * 4 + r) * 136 + wn + nt * 16 + ml] = pk[r];
            }
            if (CTb) {
                u16* ct = CTb + (long)(rowb >> 9) * SD_ + (long)col * 512 + (rowb & 511);
                *(ushort4*)ct = *(ushort4*)pk;
            }
        }
    }
    if (useEp) {
        __syncthreads();
        const int lr = tid >> 2, cs = (tid & 3) * 32;
#pragma unroll
        for (int j = 0; j < 4; ++j) {
            const s16x8 v = *(const s16x8*)&epbuf[lr * 136 + cs + j * 8];
            *(s16x8*)&Cb16[(long)(m0 + lr) * ldc + n0 + cs + j * 8] = v;
        }
    }
}

// --------------------------- pre-pass conversions ---------------------------
__global__ __launch_bounds__(256)
void cvt_k(const float* __restrict__ s, u16* __restrict__ d)
{
    const long i = ((long)blockIdx.x * 256 + threadIdx.x) * 4;
    const float4 v = *(const float4*)&s[i];
    ushort4 h = { f2bf(v.x), f2bf(v.y), f2bf(v.z), f2bf(v.w) };
    *(ushort4*)&d[i] = h;
}

// batched transpose+cvt: src[z] RxC fp32 -> dstT[z] CxR bf16 (+ optional normal copy)
__global__ __launch_bounds__(256)
void trcvt_k(const float* __restrict__ src, u16* __restrict__ dstT, u16* __restrict__ dstN,
             const int R, const int C, const long sS, const long sDT, const long sDN)
{
    __shared__ u16 t[64][72];
    const float* s = src + blockIdx.z * sS;
    const int r0 = blockIdx.y * 64, c0 = blockIdx.x * 64;
    const int tid = threadIdx.x;
    const int lr = tid >> 2, lc4 = (tid & 3) * 16;
#pragma unroll
    for (int j = 0; j < 4; ++j) {
        const float4 v = *(const float4*)&s[(long)(r0 + lr) * C + c0 + lc4 + j * 4];
        ushort4 h = { f2bf(v.x), f2bf(v.y), f2bf(v.z), f2bf(v.w) };
        *(ushort4*)&t[lr][lc4 + j * 4] = h;
        if (dstN) *(ushort4*)&dstN[blockIdx.z * sDN + (long)(r0 + lr) * C + c0 + lc4 + j * 4] = h;
    }
    __syncthreads();
    const int lcol = tid >> 2, rc = (tid & 3) * 16;
#pragma unroll
    for (int j = 0; j < 2; ++j) {
        s16x8 v;
#pragma unroll
        for (int q = 0; q < 8; ++q) v[q] = (short)t[rc + j * 8 + q][lcol];
        *(s16x8*)&dstT[blockIdx.z * sDT + (long)(c0 + lcol) * R + r0 + rc + j * 8] = v;
    }
}

// ---------------------------------------------------------------------------
__global__ __launch_bounds__(256)
void e0_k(const float* __restrict__ adj, const float* __restrict__ depmap,
          const float* __restrict__ domain_id, const float* __restrict__ redomain_id,
          float* __restrict__ invden, float* __restrict__ fa, int* __restrict__ dcol,
          int* __restrict__ dm, int* __restrict__ dsel, int* __restrict__ rm, int* __restrict__ rsel)
{
    const int bs = blockIdx.x;
    const int t = threadIdx.x;
    const float* arow = adj + (long)bs * 512;
    const float* drow = depmap + (long)bs * 512;
    __shared__ float red[256];
    __shared__ int scol;
    if (t == 0) scol = 0;
    const float a0 = arow[t], a1 = arow[t + 256];
    const float p0 = drow[t], p1 = drow[t + 256];
    if (p0 > 0.5f) scol = t;
    if (p1 > 0.5f) scol = t + 256;
    red[t] = a0 + a1;
    __syncthreads();
    for (int off = 128; off > 0; off >>= 1) { if (t < off) red[t] += red[t + off]; __syncthreads(); }
    if (t == 0) invden[bs] = 1.0f / (red[0] + 1.0f);
    __syncthreads();
    red[t] = a0 * p0 + a1 * p1;
    __syncthreads();
    for (int off = 128; off > 0; off >>= 1) { if (t < off) red[t] += red[t + off]; __syncthreads(); }
    if (t == 0) {
        fa[bs] = red[0];
        dcol[bs] = scol;
        const float* q = domain_id + (long)bs * 8;
        float s = 0.f; int sel = 0;
        for (int k = 0; k < 8; ++k) { float v = q[k]; s += v; if (v > 0.5f) sel = k; }
        dm[bs] = (s > 0.5f) ? 1 : 0; dsel[bs] = sel;
        const float* r = redomain_id + (long)bs * 8;
        s = 0.f; sel = 0;
        for (int k = 0; k < 8; ++k) { float v = r[k]; s += v; if (v > 0.5f) sel = k; }
        rm[bs] = (s > 0.5f) ? 1 : 0; rsel[bs] = sel;
    }
}

__global__ void e0b_k(const float* __restrict__ adj, const int* __restrict__ dcol, float* __restrict__ ba)
{
    const int bs = blockIdx.x * 256 + threadIdx.x;
    const int b = bs >> 9, s = bs & 511;
    ba[bs] = adj[((long)b * 512 + dcol[bs]) * 512 + s];
}

// pool pass1 (chunked masked max) + OxR^T = (OUT .* rel)^T, all bf16
__global__ __launch_bounds__(256)
void pool1_k(const u16* __restrict__ OUT, const int ldO, const int* __restrict__ domain,
             const u16* __restrict__ relb, u16* __restrict__ cm, u16* __restrict__ OxRT)
{
    const int b = blockIdx.x >> 4, c = blockIdx.x & 15;
    const int s0 = c * 32, tid = threadIdx.x;
    __shared__ int dom[256];
    dom[tid] = domain[((long)(b * 512 + s0 + (tid >> 3))) * 8 + (tid & 7)];
    __syncthreads();
    const int d0 = tid * 2;
    float mxa[8], mxb[8];
#pragma unroll
    for (int k = 0; k < 8; ++k) { mxa[k] = -10000.0f; mxb[k] = -10000.0f; }
    s16x8 pA[4], pB[4];
#pragma unroll
    for (int s = 0; s < 32; ++s) {
        const int row = b * 512 + s0 + s;
        const unsigned uv = *(const unsigned*)&OUT[(long)row * ldO + d0];
        const unsigned rv = *(const unsigned*)&relb[(long)row * 512 + d0];
        const float vx = bf2f((u16)(uv & 0xffff)), vy = bf2f((u16)(uv >> 16));
        const float rx = bf2f((u16)(rv & 0xffff)), ry = bf2f((u16)(rv >> 16));
        pA[s >> 3][s & 7] = (short)f2bf(vx * rx);
        pB[s >> 3][s & 7] = (short)f2bf(vy * ry);
        const int* ds = &dom[s * 8];
#pragma unroll
        for (int k = 0; k < 8; ++k) {
            mxa[k] = fmaxf(mxa[k], ds[k] ? -10000.0f : vx);
            mxb[k] = fmaxf(mxb[k], ds[k] ? -10000.0f : vy);
        }
    }
#pragma unroll
    for (int j = 0; j < 4; ++j) *(s16x8*)&OxRT[((long)b * 512 + d0) * 512 + s0 + j * 8] = pA[j];
#pragma unroll
    for (int j = 0; j < 4; ++j) *(s16x8*)&OxRT[((long)b * 512 + d0 + 1) * 512 + s0 + j * 8] = pB[j];
#pragma unroll
    for (int k = 0; k < 8; ++k) {
        ushort2 h = { f2bf(mxa[k]), f2bf(mxb[k]) };
        *(ushort2*)&cm[((long)((b * 16 + c) * 8 + k)) * 512 + d0] = h;
    }
}

__global__ void pool2_k(const u16* __restrict__ cm, u16* __restrict__ pooled)
{
    const int q = blockIdx.x * 256 + threadIdx.x;      // 65536
    const int b = q >> 12, k = (q >> 9) & 7, d = q & 511;
    float m = -1e30f;
    for (int c = 0; c < 16; ++c)
        m = fmaxf(m, bf2f(cm[((long)((b * 16 + c) * 8 + k)) * 512 + d]));
    pooled[((long)(b * 8 + k)) * 512 + d] = f2bf(m);
}

extern "C" void kernel_launch(void* const* d_in, const int* in_sizes, int n_in,
                              void* d_out, int out_size, void* d_ws, size_t ws_size,
                              hipStream_t stream)
{
    const float* adj         = (const float*)d_in[0];
    const int*   domain      = (const int*)d_in[1];
    const float* domain_id   = (const float*)d_in[2];
    const float* redomain_id = (const float*)d_in[3];
    const float* frontrel    = (const float*)d_in[4];
    const float* backrel     = (const float*)d_in[5];
    const float* depmap      = (const float*)d_in[6];
    const float* rel         = (const float*)d_in[7];
    const float* gcn         = (const float*)d_in[8];
    const float* W_layers    = (const float*)d_in[10];
    const float* b_layers    = (const float*)d_in[11];
    const float* prelu_a     = (const float*)d_in[12];
    const float* W_dg        = (const float*)d_in[13];
    const float* b_dg        = (const float*)d_in[14];
    const float* W_mg        = (const float*)d_in[15];
    const float* b_mg        = (const float*)d_in[16];
    const float* W_out       = (const float*)d_in[17];
    const float* b_out       = (const float*)d_in[18];
    float* out = (float*)d_out;

    char* w = (char*)d_ws;
    auto alloc = [&](size_t bytes) { void* p = (void*)w; w += (bytes + 255) & ~(size_t)255; return p; };
    const size_t Bb = (size_t)BSD_ * 2;
    u16* OUTS_bf = (u16*)alloc((size_t)8192 * 1536 * 2);
    u16* OUTT    = (u16*)alloc(Bb);   // layer output transposed [b][d][s]
    u16* gcnT    = (u16*)alloc(Bb);
    u16* RB_bf   = (u16*)alloc(Bb);   // normal [b][s][d]
    u16* XBT     = (u16*)alloc(Bb);   // [b][d][s]
    u16* XFT     = (u16*)alloc(Bb);   // [b][d][s]
    u16* OxRT    = (u16*)alloc(Bb);
    u16* DLT     = (u16*)alloc(Bb);   // [b][d][s]
    u16* AXO_bf  = (u16*)alloc(Bb);   // normal
    u16* BBT     = (u16*)alloc(Bb);   // [b][d][s]
    u16* FBT     = (u16*)alloc(Bb);
    u16* rel_bf  = (u16*)alloc(Bb);
    u16* relT_bf = (u16*)alloc(Bb);
    u16* adj_bf  = (u16*)alloc(Bb);
    u16* gcn_bf  = (u16*)alloc(Bb);
    u16* frel_bf = (u16*)alloc(Bb);
    u16* brel_bf = (u16*)alloc(Bb);
    u16* WmgT1 = (u16*)alloc((size_t)SD_ * 2);
    u16* WmgT2 = (u16*)alloc((size_t)SD_ * 2);
    u16* WdgT  = (u16*)alloc((size_t)SD_ * 2);
    u16* WlT   = (u16*)alloc((size_t)3 * SD_ * 2);
    u16* WoutT = (u16*)alloc((size_t)512 * 1536 * 2);
    u16* cm     = (u16*)alloc((size_t)16 * 16 * 8 * 512 * 2);
    u16* pooled = (u16*)alloc((size_t)16 * 8 * 512 * 2);
    float* DG     = (float*)alloc((size_t)16 * 8 * 512 * 4);
    float* invden = (float*)alloc(8192 * 4);
    float* fa     = (float*)alloc(8192 * 4);
    float* ba     = (float*)alloc(8192 * 4);
    int* dcol = (int*)alloc(8192 * 4);
    int* dm   = (int*)alloc(8192 * 4);
    int* dsel = (int*)alloc(8192 * 4);
    int* rm   = (int*)alloc(8192 * 4);
    int* rsel = (int*)alloc(8192 * 4);

    // ---- pre-pass ----
    cvt_k<<<4096, 256, 0, stream>>>(adj, adj_bf);
    cvt_k<<<4096, 256, 0, stream>>>(frontrel, frel_bf);
    cvt_k<<<4096, 256, 0, stream>>>(backrel, brel_bf);
    trcvt_k<<<dim3(8, 8, 16), 256, 0, stream>>>(gcn, gcnT, gcn_bf, 512, 512, SD_, SD_, SD_);
    trcvt_k<<<dim3(8, 8, 16), 256, 0, stream>>>(rel, relT_bf, rel_bf, 512, 512, SD_, SD_, SD_);
    trcvt_k<<<dim3(8, 8, 1), 256, 0, stream>>>(W_mg, WmgT1, nullptr, 512, 512, 0, 0, 0);
    trcvt_k<<<dim3(8, 8, 1), 256, 0, stream>>>(W_mg + SD_, WmgT2, nullptr, 512, 512, 0, 0, 0);
    trcvt_k<<<dim3(8, 8, 1), 256, 0, stream>>>(W_dg, WdgT, nullptr, 512, 512, 0, 0, 0);
    trcvt_k<<<dim3(8, 8, 3), 256, 0, stream>>>(W_layers, WlT, nullptr, 512, 512, SD_, SD_, 0);
    trcvt_k<<<dim3(8, 24, 1), 256, 0, stream>>>(W_out, WoutT, nullptr, 1536, 512, 0, 0, 0);
    e0_k<<<8192, 256, 0, stream>>>(adj, depmap, domain_id, redomain_id, invden, fa, dcol, dm, dsel, rm, rsel);
    e0b_k<<<32, 256, 0, stream>>>(adj, dcol, ba);

    const dim3 blk(512);

    // BBT/FBT = ({back,front}rel @ WmgT2 + b_mg)^T  (z=2 merged, 512 blocks)
    {
        GP p{};
        p.A1 = brel_bf; p.A2 = frel_bf; p.lda1 = p.lda2 = 512; p.sA = 0;
        p.B1 = p.B2 = WmgT2; p.ldb1 = p.ldb2 = 512; p.sB = 0;
        p.CT1 = BBT; p.CT2 = FBT; p.sCT = 0;
        p.bias = b_mg; p.M = 8192; p.K = 512; p.zs = 1; p.swzX = 2; p.swzY = 6;
        gemm3<1, 0><<<dim3(4, 64, 2), blk, 0, stream>>>(p);
    }

    for (int l = 0; l < 3; ++l) {
        const u16* OUTp  = (l == 0) ? gcn_bf : (OUTS_bf + (l - 1) * 512);
        const u16* OUTTp = (l == 0) ? gcnT : OUTT;
        const int ldO = (l == 0) ? 512 : 1536;

        // RB = rel @ outputs (B = OUT^T)
        {
            GP p{};
            p.A1 = rel_bf; p.lda1 = 512; p.sA = SD_;
            p.B1 = OUTTp; p.ldb1 = 512; p.sB = SD_;
            p.C1 = RB_bf; p.obf1 = 1; p.ldc1 = 512; p.sC = SD_;
            p.M = 512; p.K = 512; p.zs = 16; p.swzX = 2; p.swzY = 2;
            gemm3<0, 0><<<dim3(4, 4, 16), blk, 0, stream>>>(p);
        }
        pool1_k<<<256, 256, 0, stream>>>(OUTp, ldO, domain, rel_bf, cm, OxRT);
        pool2_k<<<256, 256, 0, stream>>>(cm, pooled);
        // DG = sigm(pooled @ WdgT + b_dg)  (fp32 direct)
        {
            GP p{};
            p.A1 = pooled; p.lda1 = 512; p.B1 = WdgT; p.ldb1 = 512;
            p.C1 = DG; p.obf1 = 0; p.ldc1 = 512;
            p.bias = b_dg; p.M = 128; p.K = 512; p.zs = 1; p.swzX = -1;
            gemm3<6, 0><<<dim3(4, 1, 1), blk, 0, stream>>>(p);
        }
        // gates (z=2): z0: XBT = (ba*sigm(RBeff@W1+BB)*RBeff)^T ; z1: XFT = (...)^T
        {
            GP p{};
            p.A1 = RB_bf; p.lda1 = 512; p.A2 = OUTp; p.lda2 = ldO; p.sA = 0;
            p.selm1 = rm; p.seli1 = rsel; p.selm2 = dm; p.seli2 = dsel; p.DG = DG;
            p.B1 = p.B2 = WmgT1; p.ldb1 = p.ldb2 = 512; p.sB = 0;
            p.Ci1 = BBT; p.Ci2 = FBT; p.cm1 = p.cm2 = 1; p.ldci1 = p.ldci2 = 512; p.sCi1 = p.sCi2 = 0;
            p.CT1 = XBT; p.CT2 = XFT; p.sCT = 0;
            p.sc1 = ba; p.sc2 = fa; p.M = 8192; p.K = 512; p.zs = 1; p.swzX = 2; p.swzY = 6;
            gemm3<8, 1><<<dim3(4, 64, 2), blk, 0, stream>>>(p);
        }
        // merged z=32: z<16: DLT = (relT @ XF + XB)^T ; z>=16: AXO = adj @ OxR + OUT (normal)
        {
            GP p{};
            p.A1 = relT_bf; p.lda1 = 512; p.A2 = adj_bf; p.lda2 = 512; p.sA = SD_;
            p.B1 = XFT; p.ldb1 = 512;
            p.B2 = OxRT; p.ldb2 = 512; p.sB = SD_;
            p.Ci1 = XBT; p.cm1 = 1; p.ldci1 = 512; p.sCi1 = SD_;
            p.Ci2 = OUTTp; p.cm2 = 1; p.ldci2 = 512; p.sCi2 = SD_;
            p.CT1 = DLT; p.sCT = SD_;
            p.C2 = AXO_bf; p.obf2 = 1; p.ldc2 = 512; p.sC = SD_;
            p.M = 512; p.K = 512; p.zs = 16; p.swzX = 2; p.swzY = 2;
            gemm3<3, 0><<<dim3(4, 4, 32), blk, 0, stream>>>(p);
        }
        // outs[l] = PReLU((AXO@W + 2b + DL)*invden) -> OUTS stripe (coalesced) + OUTT (transposed)
        {
            GP p{};
            p.A1 = AXO_bf; p.lda1 = 512; p.sA = SD_;
            p.B1 = WlT + (long)l * SD_; p.ldb1 = 512; p.sB = 0;
            p.Ci1 = DLT; p.cm1 = 1; p.ldci1 = 512; p.sCi1 = SD_;
            p.C1 = OUTS_bf + l * 512; p.obf1 = 1; p.ldc1 = 1536; p.sC = (long)512 * 1536;
            p.CT1 = OUTT; p.sCT = SD_;
            p.bias = b_layers + l * 512; p.bS = 2.0f;
            p.invden = invden; p.prelu = prelu_a; p.pidx = l;
            p.M = 512; p.K = 512; p.zs = 16; p.swzX = 2; p.swzY = 2;
            gemm3<4, 0><<<dim3(4, 4, 16), blk, 0, stream>>>(p);
        }
    }

    // out = OUTS @ W_out + b_out + gcn   (K=1536, fp32 direct)
    {
        GP p{};
        p.A1 = OUTS_bf; p.lda1 = 1536; p.sA = 0;
        p.B1 = WoutT; p.ldb1 = 1536; p.sB = 0;
        p.Ci1 = gcn; p.cm1 = 0; p.ldci1 = 512; p.sCi1 = 0;
        p.C1 = out; p.obf1 = 0; p.ldc1 = 512; p.sC = 0;
        p.bias = b_out; p.M = 8192; p.K = 1536; p.zs = 1; p.swzX = 2; p.swzY = 6;
        gemm3<7, 0><<<dim3(4, 64, 1), blk, 0, stream>>>(p);
    }
}